// Round 5
// baseline (418.546 us; speedup 1.0000x reference)
//
#include <hip/hip_runtime.h>
#include <math.h>

#define N_NODES 100000
#define N_EDGES 3200000
#define IN_DIM  128
#define HID     64
#define NB_SCAN ((N_NODES + 255) / 256)   // 391 scan blocks
#define N_MTILE (N_NODES / 16)            // 6250 row-tiles (exact)
#define GH_BLOCKS 8334                    // fused grid: 2084 gemm + 6250 hist

typedef unsigned int  uint;
typedef unsigned short ushort_t;
typedef __attribute__((ext_vector_type(8))) short bf16x8;
typedef __attribute__((ext_vector_type(4))) float f32x4;

// HW packed f32->bf16 (RNE): lo -> bits[15:0], hi -> bits[31:16]
__device__ __forceinline__ uint cvtpk(float lo, float hi) {
    uint r;
    asm("v_cvt_pk_bf16_f32 %0, %1, %2" : "=v"(r) : "v"(lo), "v"(hi));
    return r;
}

__device__ __forceinline__ ushort_t bf16rne(float f) {
    uint a = __float_as_uint(f);
    a = (a + 0x7fffu + ((a >> 16) & 1u)) >> 16;
    return (ushort_t)a;
}

// ---------------------------------------------------------------------------
// gemm_hist: fused independent work.
//   role gemm (blockIdx%4==0): 512 thr = 8 waves; wave w owns col-tile w of
//     [W1_l | W1_r]; B-fragments (16 VGPR) loaded once from global; block
//     grid-strides over 16-row A-tiles of x. waves 0-3 -> xlb (bf16 pairs),
//     waves 4-7 -> xr + b1 (f32).
//   role hist (else): 512 edges/block: pr[e] = (rank<<17)|dst via atomicAdd
//     on cnt[dst].
// Interleaved roles keep both populations co-resident: hist's saturated
// atomic queues overlap gemm's VALU/MFMA work.
// ---------------------------------------------------------------------------
__global__ __launch_bounds__(512) void gemm_hist(const float* __restrict__ x,
                                                 const float* __restrict__ Wl,
                                                 const float* __restrict__ Wr,
                                                 const float* __restrict__ b1,
                                                 uint* __restrict__ xlb,
                                                 float* __restrict__ xr,
                                                 const int* __restrict__ ei,
                                                 int* __restrict__ cnt,
                                                 uint* __restrict__ pr) {
    const int b = blockIdx.x;
    const int q = b >> 2;
    const int r = b & 3;

    if (r != 0) {
        // ---- hist role ----
        const int hid = q * 3 + (r - 1);           // 0..6249
        const int e   = hid * 512 + threadIdx.x;
        if (e < N_EDGES) {
            const int dst  = ei[N_EDGES + e];
            const uint rank = (uint)atomicAdd(&cnt[dst], 1);
            pr[e] = (rank << 17) | (uint)dst;
        }
        return;
    }

    // ---- gemm role ----
    const int tid  = threadIdx.x;
    const int wid  = tid >> 6;        // 0..7 = col-tile
    const int lane = tid & 63;
    const int r16  = lane & 15;       // A-row / C-col within tile
    const int kg   = lane >> 4;       // k-group

    // load B-fragments for col-tile `wid` straight from W (L2-hot, 64B/group)
    const bool left = (wid < 4);
    const int  colL = (left ? wid : wid - 4) * 16 + r16;
    const float* Wm = left ? Wl : Wr;
    bf16x8 bf[4];
    #pragma unroll
    for (int s = 0; s < 4; ++s) {
        union { ushort_t u[8]; bf16x8 v; } t;
        #pragma unroll
        for (int j = 0; j < 8; ++j) {
            const int row = s * 32 + kg * 8 + j;
            t.u[j] = bf16rne(Wm[row * 64 + colL]);
        }
        bf[s] = t.v;
    }
    const float bias = left ? 0.0f : b1[colL];

    for (int tile = q; tile < N_MTILE; tile += 2084) {
        const int row0 = tile * 16;
        const float* ap = x + (size_t)(row0 + r16) * IN_DIM + kg * 8;

        f32x4 acc = (f32x4){0.f, 0.f, 0.f, 0.f};
        #pragma unroll
        for (int s = 0; s < 4; ++s) {
            const f32x4 a0 = *(const f32x4*)(ap + s * 32);
            const f32x4 a1 = *(const f32x4*)(ap + s * 32 + 4);
            union { uint u[4]; bf16x8 v; } af;
            af.u[0] = cvtpk(a0.x, a0.y);
            af.u[1] = cvtpk(a0.z, a0.w);
            af.u[2] = cvtpk(a1.x, a1.y);
            af.u[3] = cvtpk(a1.z, a1.w);
            acc = __builtin_amdgcn_mfma_f32_16x16x32_bf16(af.v, bf[s], acc, 0, 0, 0);
        }

        if (left) {
            const int col = wid * 16 + r16;        // 0..63
            #pragma unroll
            for (int rr = 0; rr < 4; ++rr) {
                const float mine  = acc[rr];
                const float other = __shfl_xor(mine, 1);
                if ((lane & 1) == 0) {
                    const int row = row0 + kg * 4 + rr;
                    xlb[(size_t)row * 32 + (col >> 1)] = cvtpk(mine, other);
                }
            }
        } else {
            const int c = colL;                    // 0..63
            #pragma unroll
            for (int rr = 0; rr < 4; ++rr) {
                const int row = row0 + kg * 4 + rr;
                xr[(size_t)row * HID + c] = acc[rr] + bias;
            }
        }
    }
}

__global__ __launch_bounds__(256) void scanA(const int* __restrict__ cnt,
                                             int* __restrict__ incl,
                                             int* __restrict__ partial) {
    __shared__ int sh[256];
    const int tid = threadIdx.x;
    const int gid = blockIdx.x * 256 + tid;
    int v = (gid < N_NODES) ? cnt[gid] : 0;
    sh[tid] = v;
    __syncthreads();
    for (int off = 1; off < 256; off <<= 1) {
        int t = (tid >= off) ? sh[tid - off] : 0;
        __syncthreads();
        sh[tid] += t;
        __syncthreads();
    }
    if (gid < N_NODES) incl[gid] = sh[tid];
    if (tid == 255) partial[blockIdx.x] = sh[255];
}

__global__ __launch_bounds__(512) void scanB(int* __restrict__ partial) {
    __shared__ int sh[512];
    const int tid = threadIdx.x;
    int v = (tid < NB_SCAN) ? partial[tid] : 0;
    sh[tid] = v;
    __syncthreads();
    for (int off = 1; off < 512; off <<= 1) {
        int t = (tid >= off) ? sh[tid - off] : 0;
        __syncthreads();
        sh[tid] += t;
        __syncthreads();
    }
    if (tid < NB_SCAN) partial[tid] = sh[tid] - v;   // exclusive
}

__global__ __launch_bounds__(256) void scanC(const int* __restrict__ cnt,
                                             const int* __restrict__ incl,
                                             const int* __restrict__ partial,
                                             int* __restrict__ start,
                                             float* __restrict__ deg_inv) {
    const int gid = blockIdx.x * 256 + threadIdx.x;
    if (gid >= N_NODES) return;
    const int c = cnt[gid];
    start[gid]  = incl[gid] - c + partial[blockIdx.x];
    deg_inv[gid] = (c > 0) ? (1.0f / (float)c) : 0.0f;
}

// ---------------------------------------------------------------------------
// scatterIdx: pos = start[dst] + rank, both unpacked from pr. No atomics.
// ---------------------------------------------------------------------------
__global__ __launch_bounds__(256) void scatterIdx(const int* __restrict__ ei,
                                                  const int* __restrict__ start,
                                                  const uint* __restrict__ pr,
                                                  int* __restrict__ sorted_src) {
    const int e = blockIdx.x * 256 + threadIdx.x;
    if (e >= N_EDGES) return;
    const uint p = pr[e];
    const int dst  = (int)(p & 0x1FFFFu);
    const int rank = (int)(p >> 17);
    sorted_src[start[dst] + rank] = ei[e];
}

// ---------------------------------------------------------------------------
// agg1pull: wave per node; 2 neighbor rows per iteration (uint = 2 bf16/lane).
// Fused epilogue: h = relu(sum*deg_inv + xr); hl = h.W2_l; hr = h.W2_r + b2
// ---------------------------------------------------------------------------
__global__ __launch_bounds__(256) void agg1pull(const int* __restrict__ start,
                                                const int* __restrict__ cnt,
                                                const int* __restrict__ sorted_src,
                                                const uint* __restrict__ xlb,
                                                const float* __restrict__ xr,
                                                const float* __restrict__ deg_inv,
                                                const float* __restrict__ w2l,
                                                const float* __restrict__ w2r,
                                                const float* __restrict__ b2,
                                                float* __restrict__ hl,
                                                float* __restrict__ hr) {
    const int gid  = blockIdx.x * 256 + threadIdx.x;
    const int node = gid >> 6;
    const int lane = gid & 63;
    if (node >= N_NODES) return;

    const int s    = start[node];
    const int c    = cnt[node];
    const int half = lane >> 5;
    const int col2 = lane & 31;

    float sx = 0.0f, sy = 0.0f;
    for (int base = 0; base < c; base += 64) {
        const int rem = c - base;
        const int m   = rem < 64 ? rem : 64;
        int my = 0;
        if (lane < m) my = sorted_src[s + base + lane];
        for (int jj = 0; jj < m; jj += 2) {
            const int  src0 = __shfl(my, jj);
            const bool has1 = (jj + 1) < m;
            const int  src1 = has1 ? __shfl(my, jj + 1) : src0;
            const int  srcp = half ? src1 : src0;
            if (half == 0 || has1) {
                const uint v = xlb[(size_t)srcp * 32 + col2];
                sx += __uint_as_float(v << 16);
                sy += __uint_as_float(v & 0xffff0000u);
            }
        }
    }
    sx += __shfl_xor(sx, 32);
    sy += __shfl_xor(sy, 32);

    const float di  = deg_inv[node];
    const float2 xv = *(const float2*)&xr[(size_t)node * HID + 2 * col2];
    const float h0  = fmaxf(sx * di + xv.x, 0.0f);
    const float h1  = fmaxf(sy * di + xv.y, 0.0f);
    float a = h0 * w2l[2 * col2] + h1 * w2l[2 * col2 + 1];
    float b = h0 * w2r[2 * col2] + h1 * w2r[2 * col2 + 1];
    #pragma unroll
    for (int off = 16; off; off >>= 1) {
        a += __shfl_xor(a, off);
        b += __shfl_xor(b, off);
    }
    if (lane == 0) {
        hl[node] = a;
        hr[node] = b + b2[0];
    }
}

// ---------------------------------------------------------------------------
// agg2pull: wave per node. out = sigmoid(sum_j hl[j] * deg_inv + hr)
// ---------------------------------------------------------------------------
__global__ __launch_bounds__(256) void agg2pull(const int* __restrict__ start,
                                                const int* __restrict__ cnt,
                                                const int* __restrict__ sorted_src,
                                                const float* __restrict__ hl,
                                                const float* __restrict__ hr,
                                                const float* __restrict__ deg_inv,
                                                float* __restrict__ out) {
    const int gid  = blockIdx.x * 256 + threadIdx.x;
    const int node = gid >> 6;
    const int lane = gid & 63;
    if (node >= N_NODES) return;

    const int s = start[node];
    const int c = cnt[node];

    float sum = 0.0f;
    for (int j = lane; j < c; j += 64) {
        sum += hl[sorted_src[s + j]];
    }
    #pragma unroll
    for (int off = 32; off; off >>= 1) sum += __shfl_xor(sum, off);

    if (lane == 0) {
        const float z = sum * deg_inv[node] + hr[node];
        out[node] = 1.0f / (1.0f + expf(-z));
    }
}

extern "C" void kernel_launch(void* const* d_in, const int* in_sizes, int n_in,
                              void* d_out, int out_size, void* d_ws, size_t ws_size,
                              hipStream_t stream) {
    const float* x    = (const float*)d_in[0];
    const int*   ei   = (const int*)  d_in[1];
    const float* W1l  = (const float*)d_in[2];
    const float* b1   = (const float*)d_in[3];
    const float* W1r  = (const float*)d_in[4];
    const float* W2l  = (const float*)d_in[5];
    const float* b2   = (const float*)d_in[6];
    const float* W2r  = (const float*)d_in[7];
    float* out = (float*)d_out;

    char* wsb = (char*)d_ws;
    const size_t N = N_NODES;
    uint*  xlb     = (uint*)wsb;                         wsb += 32 * N * 4;
    float* xr      = (float*)wsb;                        wsb += 64 * N * 4;
    float* hl      = (float*)wsb;                        wsb += N * 4;
    float* hr      = (float*)wsb;                        wsb += N * 4;
    float* deg_inv = (float*)wsb;                        wsb += N * 4;
    int*   cnt     = (int*)wsb;                          wsb += N * 4;
    int*   incl    = (int*)wsb;                          wsb += N * 4;
    int*   startA  = (int*)wsb;                          wsb += N * 4;
    uint*  pr      = (uint*)wsb;                         wsb += (size_t)N_EDGES * 4;
    int*   partial = (int*)wsb;                          wsb += 512 * 4;
    int*   ssrc    = (int*)wsb;                          wsb += (size_t)N_EDGES * 4;

    hipMemsetAsync(cnt, 0, N * sizeof(int), stream);

    gemm_hist<<<GH_BLOCKS, 512, 0, stream>>>(x, W1l, W1r, b1, xlb, xr, ei, cnt, pr);

    scanA<<<NB_SCAN, 256, 0, stream>>>(cnt, incl, partial);
    scanB<<<1, 512, 0, stream>>>(partial);
    scanC<<<NB_SCAN, 256, 0, stream>>>(cnt, incl, partial, startA, deg_inv);

    const int eb = (N_EDGES + 255) / 256;
    scatterIdx<<<eb, 256, 0, stream>>>(ei, startA, pr, ssrc);

    {
        const long long total = (long long)N_NODES * 64;
        const int blocks = (int)((total + 255) / 256);
        agg1pull<<<blocks, 256, 0, stream>>>(startA, cnt, ssrc, xlb, xr, deg_inv,
                                             W2l, W2r, b2, hl, hr);
        agg2pull<<<blocks, 256, 0, stream>>>(startA, cnt, ssrc, hl, hr, deg_inv, out);
    }
}

// Round 6
// 263.898 us; speedup vs baseline: 1.5860x; 1.5860x over previous
//
#include <hip/hip_runtime.h>
#include <math.h>

#define N_NODES 100000
#define N_EDGES 3200000
#define IN_DIM  128
#define HID     64
#define N_MTILE (N_NODES / 16)            // 6250 row-tiles (exact)

// binning-sort geometry
#define E_BLK    8192
#define NBLK_BIN ((N_EDGES + E_BLK - 1) / E_BLK)   // 391
#define BUCKETS  500
#define BRANGE   200                                // 500*200 = 100000 exact
#define MT_LEN   (BUCKETS * NBLK_BIN)               // 195500
#define NB_SA2   ((MT_LEN + 255) / 256)             // 764 scan blocks

typedef unsigned int  uint;
typedef unsigned short ushort_t;
typedef __attribute__((ext_vector_type(8))) short bf16x8;
typedef __attribute__((ext_vector_type(4))) float f32x4;

// HW packed f32->bf16 (RNE): lo -> bits[15:0], hi -> bits[31:16]
__device__ __forceinline__ uint cvtpk(float lo, float hi) {
    uint r;
    asm("v_cvt_pk_bf16_f32 %0, %1, %2" : "=v"(r) : "v"(lo), "v"(hi));
    return r;
}

// ---------------------------------------------------------------------------
// wrepack: lay W = [W1_l | W1_r] (128x128) out in per-lane B-fragment order
// for v_mfma_f32_16x16x32_bf16 (t=col-tile, s=k-step, l=lane, j=k-elem):
//   wpk[((t*4+s)*64+l)*8+j] = bf16( W[s*32+(l>>4)*8+j][t*16+(l&15)] )
// ---------------------------------------------------------------------------
__global__ __launch_bounds__(256) void wrepack(const float* __restrict__ Wl,
                                               const float* __restrict__ Wr,
                                               ushort_t* __restrict__ wpk) {
    const int idx = blockIdx.x * 256 + threadIdx.x;
    if (idx >= 128 * 128) return;
    const int j = idx & 7;
    const int l = (idx >> 3) & 63;
    const int s = (idx >> 9) & 3;
    const int t = idx >> 11;
    const int row = s * 32 + ((l >> 4) << 3) + j;
    const int col = t * 16 + (l & 15);
    const float v = (col < 64) ? Wl[row * 64 + col] : Wr[row * 64 + (col - 64)];
    uint a = __float_as_uint(v);
    a = (a + 0x7fffu + ((a >> 16) & 1u)) >> 16;
    wpk[idx] = (ushort_t)a;
}

// ---------------------------------------------------------------------------
// gemm1m: MFMA gemm, 1 row-tile per block (grid 6250), 4 waves = 8 col-tiles.
// Wave w owns col-tiles {2w,2w+1}: waves 0,1 -> xlb (bf16), 2,3 -> xr (+b1).
// ---------------------------------------------------------------------------
__global__ __launch_bounds__(256) void gemm1m(const float* __restrict__ x,
                                              const ushort_t* __restrict__ wpk,
                                              const float* __restrict__ b1,
                                              uint* __restrict__ xlb,
                                              float* __restrict__ xr) {
    const int tid  = threadIdx.x;
    const int wid  = tid >> 6;
    const int lane = tid & 63;
    const int t0   = wid * 2;
    const int r16  = lane & 15;   // A-row / C-col within tile
    const int kg   = lane >> 4;   // k-group

    bf16x8 bf[2][4];
    #pragma unroll
    for (int tt = 0; tt < 2; ++tt)
        #pragma unroll
        for (int s = 0; s < 4; ++s)
            bf[tt][s] = *(const bf16x8*)&wpk[(((size_t)(t0 + tt) * 4 + s) * 64 + lane) * 8];

    float bias[2] = {0.f, 0.f};
    if (wid >= 2) {
        bias[0] = b1[(t0 + 0) * 16 + r16 - 64];
        bias[1] = b1[(t0 + 1) * 16 + r16 - 64];
    }

    for (int tile = blockIdx.x; tile < N_MTILE; tile += gridDim.x) {
        const int row0 = tile * 16;
        const float* ap = x + (size_t)(row0 + r16) * IN_DIM + kg * 8;

        f32x4 acc[2];
        acc[0] = (f32x4){0.f, 0.f, 0.f, 0.f};
        acc[1] = (f32x4){0.f, 0.f, 0.f, 0.f};

        #pragma unroll
        for (int s = 0; s < 4; ++s) {
            const f32x4 a0 = *(const f32x4*)(ap + s * 32);
            const f32x4 a1 = *(const f32x4*)(ap + s * 32 + 4);
            union { uint u[4]; bf16x8 v; } af;
            af.u[0] = cvtpk(a0.x, a0.y);
            af.u[1] = cvtpk(a0.z, a0.w);
            af.u[2] = cvtpk(a1.x, a1.y);
            af.u[3] = cvtpk(a1.z, a1.w);
            acc[0] = __builtin_amdgcn_mfma_f32_16x16x32_bf16(af.v, bf[0][s], acc[0], 0, 0, 0);
            acc[1] = __builtin_amdgcn_mfma_f32_16x16x32_bf16(af.v, bf[1][s], acc[1], 0, 0, 0);
        }

        if (wid < 2) {
            #pragma unroll
            for (int tt = 0; tt < 2; ++tt) {
                const int col = (t0 + tt) * 16 + r16;
                #pragma unroll
                for (int r = 0; r < 4; ++r) {
                    const float mine  = acc[tt][r];
                    const float other = __shfl_xor(mine, 1);
                    if ((lane & 1) == 0) {
                        const int row = row0 + kg * 4 + r;
                        xlb[(size_t)row * 32 + (col >> 1)] = cvtpk(mine, other);
                    }
                }
            }
        } else {
            #pragma unroll
            for (int tt = 0; tt < 2; ++tt) {
                const int c = (t0 + tt) * 16 + r16 - 64;
                #pragma unroll
                for (int r = 0; r < 4; ++r) {
                    const int row = row0 + kg * 4 + r;
                    xr[(size_t)row * HID + c] = acc[tt][r] + bias[tt];
                }
            }
        }
    }
}

// ---------------------------------------------------------------------------
// binHist: per (edge-block, bucket) histogram via LDS atomics.
// MT is bucket-major: MT[b * NBLK_BIN + blk]
// ---------------------------------------------------------------------------
__global__ __launch_bounds__(256) void binHist(const int* __restrict__ ei,
                                               int* __restrict__ MT) {
    __shared__ int h[BUCKETS];
    for (int j = threadIdx.x; j < BUCKETS; j += 256) h[j] = 0;
    __syncthreads();
    const int e0 = blockIdx.x * E_BLK;
    const int e1 = min(e0 + E_BLK, N_EDGES);
    for (int e = e0 + threadIdx.x; e < e1; e += 256)
        atomicAdd(&h[ei[N_EDGES + e] / BRANGE], 1);
    __syncthreads();
    for (int j = threadIdx.x; j < BUCKETS; j += 256)
        MT[j * NBLK_BIN + blockIdx.x] = h[j];
}

// exclusive scan of MT (length MT_LEN) -> MTi, 3 small kernels
__global__ __launch_bounds__(256) void scanA2(const int* __restrict__ MT,
                                              int* __restrict__ MTi,
                                              int* __restrict__ partial) {
    __shared__ int sh[256];
    const int tid = threadIdx.x;
    const int gid = blockIdx.x * 256 + tid;
    int v = (gid < MT_LEN) ? MT[gid] : 0;
    sh[tid] = v;
    __syncthreads();
    for (int off = 1; off < 256; off <<= 1) {
        int t = (tid >= off) ? sh[tid - off] : 0;
        __syncthreads();
        sh[tid] += t;
        __syncthreads();
    }
    if (gid < MT_LEN) MTi[gid] = sh[tid];
    if (tid == 255) partial[blockIdx.x] = sh[255];
}

__global__ __launch_bounds__(1024) void scanB2(int* __restrict__ partial) {
    __shared__ int sh[1024];
    const int tid = threadIdx.x;
    int v = (tid < NB_SA2) ? partial[tid] : 0;
    sh[tid] = v;
    __syncthreads();
    for (int off = 1; off < 1024; off <<= 1) {
        int t = (tid >= off) ? sh[tid - off] : 0;
        __syncthreads();
        sh[tid] += t;
        __syncthreads();
    }
    if (tid < NB_SA2) partial[tid] = sh[tid] - v;   // exclusive
}

__global__ __launch_bounds__(256) void scanC2(const int* __restrict__ MT,
                                              int* __restrict__ MTi,
                                              const int* __restrict__ partial) {
    const int gid = blockIdx.x * 256 + threadIdx.x;
    if (gid >= MT_LEN) return;
    MTi[gid] = MTi[gid] + partial[blockIdx.x] - MT[gid];   // exclusive scan
}

// ---------------------------------------------------------------------------
// binScatter: write (src,dst) pairs into bucket-major segments; position =
// MTi[b*NBLK_BIN + blk] + LDS-cursor rank. No global atomics.
// ---------------------------------------------------------------------------
__global__ __launch_bounds__(256) void binScatter(const int* __restrict__ ei,
                                                  const int* __restrict__ MTi,
                                                  uint2* __restrict__ pairs) {
    __shared__ int cur[BUCKETS];
    for (int j = threadIdx.x; j < BUCKETS; j += 256)
        cur[j] = MTi[j * NBLK_BIN + blockIdx.x];
    __syncthreads();
    const int e0 = blockIdx.x * E_BLK;
    const int e1 = min(e0 + E_BLK, N_EDGES);
    for (int e = e0 + threadIdx.x; e < e1; e += 256) {
        const int dst = ei[N_EDGES + e];
        const int src = ei[e];
        const int pos = atomicAdd(&cur[dst / BRANGE], 1);
        pairs[pos] = make_uint2((uint)src, (uint)dst);
    }
}

// ---------------------------------------------------------------------------
// bucketCSR: one block per bucket (200 nodes, ~6400 edges). LDS count+scan
// -> startA/cnt/deg_inv, then LDS-cursor scatter of src into final ssrc.
// ---------------------------------------------------------------------------
__global__ __launch_bounds__(256) void bucketCSR(const uint2* __restrict__ pairs,
                                                 const int* __restrict__ MTi,
                                                 int* __restrict__ startA,
                                                 int* __restrict__ cnt,
                                                 float* __restrict__ deg_inv,
                                                 int* __restrict__ ssrc) {
    __shared__ int h[BRANGE];
    __shared__ int curs[BRANGE];
    __shared__ int sc[256];
    const int tid = threadIdx.x;
    const int b   = blockIdx.x;
    const int n0  = b * BRANGE;

    for (int j = tid; j < BRANGE; j += 256) h[j] = 0;
    __syncthreads();

    const int bs = MTi[b * NBLK_BIN];
    const int be = (b + 1 < BUCKETS) ? MTi[(b + 1) * NBLK_BIN] : N_EDGES;

    for (int e = bs + tid; e < be; e += 256)
        atomicAdd(&h[(int)pairs[e].y - n0], 1);
    __syncthreads();

    // inclusive scan of h[0..199] over 256 lanes
    sc[tid] = (tid < BRANGE) ? h[tid] : 0;
    __syncthreads();
    for (int off = 1; off < 256; off <<= 1) {
        int t = (tid >= off) ? sc[tid - off] : 0;
        __syncthreads();
        sc[tid] += t;
        __syncthreads();
    }
    if (tid < BRANGE) {
        const int c  = h[tid];
        const int st = bs + sc[tid] - c;   // exclusive
        const int node = n0 + tid;
        startA[node]  = st;
        cnt[node]     = c;
        deg_inv[node] = (c > 0) ? (1.0f / (float)c) : 0.0f;
        curs[tid]     = st;
    }
    __syncthreads();

    for (int e = bs + tid; e < be; e += 256) {
        const uint2 p = pairs[e];
        const int r = atomicAdd(&curs[(int)p.y - n0], 1);
        ssrc[r] = (int)p.x;
    }
}

// ---------------------------------------------------------------------------
// agg1pull: wave per node; 2 neighbor rows per iteration (uint = 2 bf16/lane).
// Fused epilogue: h = relu(sum*deg_inv + xr); hl = h.W2_l; hr = h.W2_r + b2
// ---------------------------------------------------------------------------
__global__ __launch_bounds__(256) void agg1pull(const int* __restrict__ start,
                                                const int* __restrict__ cnt,
                                                const int* __restrict__ sorted_src,
                                                const uint* __restrict__ xlb,
                                                const float* __restrict__ xr,
                                                const float* __restrict__ deg_inv,
                                                const float* __restrict__ w2l,
                                                const float* __restrict__ w2r,
                                                const float* __restrict__ b2,
                                                float* __restrict__ hl,
                                                float* __restrict__ hr) {
    const int gid  = blockIdx.x * 256 + threadIdx.x;
    const int node = gid >> 6;
    const int lane = gid & 63;
    if (node >= N_NODES) return;

    const int s    = start[node];
    const int c    = cnt[node];
    const int half = lane >> 5;
    const int col2 = lane & 31;

    float sx = 0.0f, sy = 0.0f;
    for (int base = 0; base < c; base += 64) {
        const int rem = c - base;
        const int m   = rem < 64 ? rem : 64;
        int my = 0;
        if (lane < m) my = sorted_src[s + base + lane];
        for (int jj = 0; jj < m; jj += 2) {
            const int  src0 = __shfl(my, jj);
            const bool has1 = (jj + 1) < m;
            const int  src1 = has1 ? __shfl(my, jj + 1) : src0;
            const int  srcp = half ? src1 : src0;
            if (half == 0 || has1) {
                const uint v = xlb[(size_t)srcp * 32 + col2];
                sx += __uint_as_float(v << 16);
                sy += __uint_as_float(v & 0xffff0000u);
            }
        }
    }
    sx += __shfl_xor(sx, 32);
    sy += __shfl_xor(sy, 32);

    const float di  = deg_inv[node];
    const float2 xv = *(const float2*)&xr[(size_t)node * HID + 2 * col2];
    const float h0  = fmaxf(sx * di + xv.x, 0.0f);
    const float h1  = fmaxf(sy * di + xv.y, 0.0f);
    float a = h0 * w2l[2 * col2] + h1 * w2l[2 * col2 + 1];
    float b = h0 * w2r[2 * col2] + h1 * w2r[2 * col2 + 1];
    #pragma unroll
    for (int off = 16; off; off >>= 1) {
        a += __shfl_xor(a, off);
        b += __shfl_xor(b, off);
    }
    if (lane == 0) {
        hl[node] = a;
        hr[node] = b + b2[0];
    }
}

// ---------------------------------------------------------------------------
// agg2pull: wave per node. out = sigmoid(sum_j hl[j] * deg_inv + hr)
// ---------------------------------------------------------------------------
__global__ __launch_bounds__(256) void agg2pull(const int* __restrict__ start,
                                                const int* __restrict__ cnt,
                                                const int* __restrict__ sorted_src,
                                                const float* __restrict__ hl,
                                                const float* __restrict__ hr,
                                                const float* __restrict__ deg_inv,
                                                float* __restrict__ out) {
    const int gid  = blockIdx.x * 256 + threadIdx.x;
    const int node = gid >> 6;
    const int lane = gid & 63;
    if (node >= N_NODES) return;

    const int s = start[node];
    const int c = cnt[node];

    float sum = 0.0f;
    for (int j = lane; j < c; j += 64) {
        sum += hl[sorted_src[s + j]];
    }
    #pragma unroll
    for (int off = 32; off; off >>= 1) sum += __shfl_xor(sum, off);

    if (lane == 0) {
        const float z = sum * deg_inv[node] + hr[node];
        out[node] = 1.0f / (1.0f + expf(-z));
    }
}

extern "C" void kernel_launch(void* const* d_in, const int* in_sizes, int n_in,
                              void* d_out, int out_size, void* d_ws, size_t ws_size,
                              hipStream_t stream) {
    const float* x    = (const float*)d_in[0];
    const int*   ei   = (const int*)  d_in[1];
    const float* W1l  = (const float*)d_in[2];
    const float* b1   = (const float*)d_in[3];
    const float* W1r  = (const float*)d_in[4];
    const float* W2l  = (const float*)d_in[5];
    const float* b2   = (const float*)d_in[6];
    const float* W2r  = (const float*)d_in[7];
    float* out = (float*)d_out;

    char* wsb = (char*)d_ws;
    const size_t N = N_NODES;
    uint*     xlb     = (uint*)wsb;      wsb += 32 * N * 4;
    float*    xr      = (float*)wsb;     wsb += 64 * N * 4;
    float*    hl      = (float*)wsb;     wsb += N * 4;
    float*    hr      = (float*)wsb;     wsb += N * 4;
    float*    deg_inv = (float*)wsb;     wsb += N * 4;
    int*      cnt     = (int*)wsb;       wsb += N * 4;
    int*      startA  = (int*)wsb;       wsb += N * 4;
    int*      MT      = (int*)wsb;       wsb += (size_t)MT_LEN * 4;
    int*      MTi     = (int*)wsb;       wsb += (size_t)MT_LEN * 4;
    int*      partial = (int*)wsb;       wsb += 1024 * 4;
    uint2*    pairs   = (uint2*)wsb;     wsb += (size_t)N_EDGES * 8;
    int*      ssrc    = (int*)wsb;       wsb += (size_t)N_EDGES * 4;
    ushort_t* wpk     = (ushort_t*)wsb;  wsb += 128 * 128 * 2;

    // independent dense path
    wrepack<<<64, 256, 0, stream>>>(W1l, W1r, wpk);
    gemm1m<<<N_MTILE, 256, 0, stream>>>(x, wpk, b1, xlb, xr);

    // CSR build, atomic-free (LDS only)
    binHist<<<NBLK_BIN, 256, 0, stream>>>(ei, MT);
    scanA2<<<NB_SA2, 256, 0, stream>>>(MT, MTi, partial);
    scanB2<<<1, 1024, 0, stream>>>(partial);
    scanC2<<<NB_SA2, 256, 0, stream>>>(MT, MTi, partial);
    binScatter<<<NBLK_BIN, 256, 0, stream>>>(ei, MTi, pairs);
    bucketCSR<<<BUCKETS, 256, 0, stream>>>(pairs, MTi, startA, cnt, deg_inv, ssrc);

    // pull-aggregations
    {
        const long long total = (long long)N_NODES * 64;
        const int blocks = (int)((total + 255) / 256);
        agg1pull<<<blocks, 256, 0, stream>>>(startA, cnt, ssrc, xlb, xr, deg_inv,
                                             W2l, W2r, b2, hl, hr);
        agg2pull<<<blocks, 256, 0, stream>>>(startA, cnt, ssrc, hl, hr, deg_inv, out);
    }
}